// Round 5
// baseline (121.674 us; speedup 1.0000x reference)
//
#include <hip/hip_runtime.h>

#define LN_EPS 1e-5f

__device__ __forceinline__ float wred_max(float v) {
#pragma unroll
    for (int off = 32; off; off >>= 1) v = fmaxf(v, __shfl_xor(v, off, 64));
    return v;
}
__device__ __forceinline__ float wred_sum(float v) {
#pragma unroll
    for (int off = 32; off; off >>= 1) v += __shfl_xor(v, off, 64);
    return v;
}

// ---------------- Kernel 1: dual GEMM, 8 cols/lane, LDS-lean ----------------
// hi_ws[row][e] = x[row]·W1[:256][e] + b1[e];  hjT[b][d][m] = x[row]·W1[256:][d]
// 512 blocks = 8 batch × 32 rowgroups(8 rows) × 2 W1-halves; 256 thr / 4 waves.
// Lane owns 1 row (lane&7) × 8 cols (c0 = w*64 + (lane>>3)*8) × 256 k.
// vs R0/R4: LDS reads per wave 256→64 ds_read_b128 (the R0 bottleneck:
// 8 waves/CU × 256 × 12cy = 10.2 µs on the shared LDS pipe → now 2.6 µs).
// xs rows padded to 260 floats: read banks (4r+4c)%32..+3 disjoint across
// the 8 rows → conflict-free. Each wave reads a distinct 64-col W slice
// once → W/block = 256 KB (keeps R4's traffic halving, 16.4 MB/XCD).

#define WL(Q, XQ, C) {                                                          \
    XQ = *(const float4*)&xs[row_local][(C) * 4];                               \
    const float* _wp = Wb + (size_t)((C) * 4) * 256;                            \
    _Pragma("unroll") for (int _j = 0; _j < 4; _j++) {                          \
        Q[2 * _j]     = *(const float4*)(_wp + (size_t)_j * 256);               \
        Q[2 * _j + 1] = *(const float4*)(_wp + (size_t)_j * 256 + 4); } }

#define WC(Q, XQ) {                                                             \
    const float _xv[4] = {XQ.x, XQ.y, XQ.z, XQ.w};                              \
    _Pragma("unroll") for (int _j = 0; _j < 4; _j++) {                          \
        acc[0] = fmaf(_xv[_j], Q[2 * _j].x, acc[0]);                            \
        acc[1] = fmaf(_xv[_j], Q[2 * _j].y, acc[1]);                            \
        acc[2] = fmaf(_xv[_j], Q[2 * _j].z, acc[2]);                            \
        acc[3] = fmaf(_xv[_j], Q[2 * _j].w, acc[3]);                            \
        acc[4] = fmaf(_xv[_j], Q[2 * _j + 1].x, acc[4]);                        \
        acc[5] = fmaf(_xv[_j], Q[2 * _j + 1].y, acc[5]);                        \
        acc[6] = fmaf(_xv[_j], Q[2 * _j + 1].z, acc[6]);                        \
        acc[7] = fmaf(_xv[_j], Q[2 * _j + 1].w, acc[7]); } }

__global__ __launch_bounds__(256, 2) void k_gemm_hij(
    const float* __restrict__ x,    // [2048,256]
    const float* __restrict__ W1,   // [512,256]
    const float* __restrict__ b1,   // [256]
    float* __restrict__ hi_ws,      // [2048,256]
    float* __restrict__ hjT)        // [8,256,256] (b, d, m)
{
    __shared__ __align__(16) float xs[8][260];   // +4 pad: conflict-free reads
    const int t = threadIdx.x;
    const int lane = t & 63, w = t >> 6;
    const int b = blockIdx.x & 7;           // batch (XCD-local)
    const int idx = blockIdx.x >> 3;        // 0..63
    const int rg = idx & 31;                // row-group of 8 rows
    const int half = idx >> 5;              // W1 half: 0 -> hi, 1 -> hjT
    const int mrow0 = rg * 8;               // batch-local first row of block

    {   // stage 8 rows of x; thread t: row t>>5, cols (t&31)*8..+7
        const int sr = t >> 5;
        const int sc = (t & 31) * 8;
        const float* sp = x + (size_t)(b * 256 + mrow0 + sr) * 256 + sc;
        *(float4*)&xs[sr][sc]     = *(const float4*)sp;
        *(float4*)&xs[sr][sc + 4] = *(const float4*)(sp + 4);
    }
    __syncthreads();

    const int row_local = lane & 7;                  // lane's row 0..7
    const int c0 = w * 64 + (lane >> 3) * 8;         // lane's col base 0..255
    const float* Wb = W1 + (size_t)half * 65536 + c0;

    float acc[8];
#pragma unroll
    for (int j = 0; j < 8; j++) acc[j] = 0.f;

    float4 qa[8], qb[8];
    float4 xa, xb;
    WL(qa, xa, 0);
    for (int c = 0; c + 2 < 64; c += 2) {
        WL(qb, xb, c + 1);
        WC(qa, xa);
        WL(qa, xa, c + 2);
        WC(qb, xb);
    }
    WL(qb, xb, 63);
    WC(qa, xa);
    WC(qb, xb);

    if (half == 0) {
        const float4 bb0 = *(const float4*)(b1 + c0);
        const float4 bb1 = *(const float4*)(b1 + c0 + 4);
        float* dst = hi_ws + (size_t)(b * 256 + mrow0 + row_local) * 256 + c0;
        *(float4*)dst = make_float4(acc[0] + bb0.x, acc[1] + bb0.y,
                                    acc[2] + bb0.z, acc[3] + bb0.w);
        *(float4*)(dst + 4) = make_float4(acc[4] + bb1.x, acc[5] + bb1.y,
                                          acc[6] + bb1.z, acc[7] + bb1.w);
    } else {
        const int m = mrow0 + row_local;
        float* base = hjT + (size_t)b * 65536 + (size_t)c0 * 256 + m;
#pragma unroll
        for (int j = 0; j < 8; j++) base[(size_t)j * 256] = acc[j];
    }
}

// ---------------- Kernel 2: fused (round-0 proven, verbatim) ----------------
// 4 n's per block, 512 blocks × 4 waves (2 blocks/CU), XCD swizzle b=blockIdx&7.

// phase 1: groups of 4 d-rows (4 float4 loads), compute 192 VALU/group
#define P1L(H, G) { const float* _p = hjp + (size_t)((G) * 4) * 256;            \
    _Pragma("unroll") for (int _j = 0; _j < 4; _j++)                            \
        H[_j] = *(const float4*)(_p + (size_t)_j * 256); }

#define P1C(H, G) { const int _db = w * 64 + (G) * 4;                           \
    float4 _wq = *(const float4*)&w2_s[_db];                                    \
    _Pragma("unroll") for (int _n = 0; _n < 4; _n++) {                          \
        float4 _h4 = *(const float4*)&hi_s[_n][_db];                            \
        sp[_n][0] = fmaf(fmaxf(_h4.x + H[0].x, 0.f), _wq.x, sp[_n][0]);         \
        sp[_n][0] = fmaf(fmaxf(_h4.y + H[1].x, 0.f), _wq.y, sp[_n][0]);         \
        sp[_n][0] = fmaf(fmaxf(_h4.z + H[2].x, 0.f), _wq.z, sp[_n][0]);         \
        sp[_n][0] = fmaf(fmaxf(_h4.w + H[3].x, 0.f), _wq.w, sp[_n][0]);         \
        sp[_n][1] = fmaf(fmaxf(_h4.x + H[0].y, 0.f), _wq.x, sp[_n][1]);         \
        sp[_n][1] = fmaf(fmaxf(_h4.y + H[1].y, 0.f), _wq.y, sp[_n][1]);         \
        sp[_n][1] = fmaf(fmaxf(_h4.z + H[2].y, 0.f), _wq.z, sp[_n][1]);         \
        sp[_n][1] = fmaf(fmaxf(_h4.w + H[3].y, 0.f), _wq.w, sp[_n][1]);         \
        sp[_n][2] = fmaf(fmaxf(_h4.x + H[0].z, 0.f), _wq.x, sp[_n][2]);         \
        sp[_n][2] = fmaf(fmaxf(_h4.y + H[1].z, 0.f), _wq.y, sp[_n][2]);         \
        sp[_n][2] = fmaf(fmaxf(_h4.z + H[2].z, 0.f), _wq.z, sp[_n][2]);         \
        sp[_n][2] = fmaf(fmaxf(_h4.w + H[3].z, 0.f), _wq.w, sp[_n][2]);         \
        sp[_n][3] = fmaf(fmaxf(_h4.x + H[0].w, 0.f), _wq.x, sp[_n][3]);         \
        sp[_n][3] = fmaf(fmaxf(_h4.y + H[1].w, 0.f), _wq.y, sp[_n][3]);         \
        sp[_n][3] = fmaf(fmaxf(_h4.z + H[2].w, 0.f), _wq.z, sp[_n][3]);         \
        sp[_n][3] = fmaf(fmaxf(_h4.w + H[3].w, 0.f), _wq.w, sp[_n][3]); } }

// phases 2/3: groups of 8 rows (8 float4 loads), dot with LDS weight rows
#define DLOAD(X, PTR, G) { const float* _p = (PTR) + (size_t)((G) * 8) * 256;   \
    _Pragma("unroll") for (int _j = 0; _j < 8; _j++)                            \
        X[_j] = *(const float4*)(_p + (size_t)_j * 256); }

#define DCOMP(ACCV, WS, X, G) { const int _rb = w * 64 + (G) * 8;               \
    _Pragma("unroll") for (int _n = 0; _n < 4; _n++) {                          \
        float4 _wa = *(const float4*)&WS[_n][_rb];                              \
        float4 _wb = *(const float4*)&WS[_n][_rb + 4];                          \
        ACCV[_n][0] = fmaf(_wa.x, X[0].x, ACCV[_n][0]);                         \
        ACCV[_n][0] = fmaf(_wa.y, X[1].x, ACCV[_n][0]);                         \
        ACCV[_n][0] = fmaf(_wa.z, X[2].x, ACCV[_n][0]);                         \
        ACCV[_n][0] = fmaf(_wa.w, X[3].x, ACCV[_n][0]);                         \
        ACCV[_n][0] = fmaf(_wb.x, X[4].x, ACCV[_n][0]);                         \
        ACCV[_n][0] = fmaf(_wb.y, X[5].x, ACCV[_n][0]);                         \
        ACCV[_n][0] = fmaf(_wb.z, X[6].x, ACCV[_n][0]);                         \
        ACCV[_n][0] = fmaf(_wb.w, X[7].x, ACCV[_n][0]);                         \
        ACCV[_n][1] = fmaf(_wa.x, X[0].y, ACCV[_n][1]);                         \
        ACCV[_n][1] = fmaf(_wa.y, X[1].y, ACCV[_n][1]);                         \
        ACCV[_n][1] = fmaf(_wa.z, X[2].y, ACCV[_n][1]);                         \
        ACCV[_n][1] = fmaf(_wa.w, X[3].y, ACCV[_n][1]);                         \
        ACCV[_n][1] = fmaf(_wb.x, X[4].y, ACCV[_n][1]);                         \
        ACCV[_n][1] = fmaf(_wb.y, X[5].y, ACCV[_n][1]);                         \
        ACCV[_n][1] = fmaf(_wb.z, X[6].y, ACCV[_n][1]);                         \
        ACCV[_n][1] = fmaf(_wb.w, X[7].y, ACCV[_n][1]);                         \
        ACCV[_n][2] = fmaf(_wa.x, X[0].z, ACCV[_n][2]);                         \
        ACCV[_n][2] = fmaf(_wa.y, X[1].z, ACCV[_n][2]);                         \
        ACCV[_n][2] = fmaf(_wa.z, X[2].z, ACCV[_n][2]);                         \
        ACCV[_n][2] = fmaf(_wa.w, X[3].z, ACCV[_n][2]);                         \
        ACCV[_n][2] = fmaf(_wb.x, X[4].z, ACCV[_n][2]);                         \
        ACCV[_n][2] = fmaf(_wb.y, X[5].z, ACCV[_n][2]);                         \
        ACCV[_n][2] = fmaf(_wb.z, X[6].z, ACCV[_n][2]);                         \
        ACCV[_n][2] = fmaf(_wb.w, X[7].z, ACCV[_n][2]);                         \
        ACCV[_n][3] = fmaf(_wa.x, X[0].w, ACCV[_n][3]);                         \
        ACCV[_n][3] = fmaf(_wa.y, X[1].w, ACCV[_n][3]);                         \
        ACCV[_n][3] = fmaf(_wa.z, X[2].w, ACCV[_n][3]);                         \
        ACCV[_n][3] = fmaf(_wa.w, X[3].w, ACCV[_n][3]);                         \
        ACCV[_n][3] = fmaf(_wb.x, X[4].w, ACCV[_n][3]);                         \
        ACCV[_n][3] = fmaf(_wb.y, X[5].w, ACCV[_n][3]);                         \
        ACCV[_n][3] = fmaf(_wb.z, X[6].w, ACCV[_n][3]);                         \
        ACCV[_n][3] = fmaf(_wb.w, X[7].w, ACCV[_n][3]); } }

__global__ __launch_bounds__(256) void k_fused(
    const float* __restrict__ x,      // [8,256,256]
    const float* __restrict__ hi_ws,  // [2048,256] (b1 folded)
    const float* __restrict__ hjT,    // [8,256,256] (b, d, m)
    const float* __restrict__ W2, const float* __restrict__ b2,
    const float* __restrict__ Wp, const float* __restrict__ bp,
    const float* __restrict__ gma, const float* __restrict__ bta,
    float* __restrict__ out)
{
    const int t = threadIdx.x;
    const int lane = t & 63, w = t >> 6;
    const int b = blockIdx.x & 7;          // XCD-local batch
    const int n0 = (blockIdx.x >> 3) * 4;  // n-tile within batch
    const int bn0 = b * 256 + n0;

    __shared__ __align__(16) float hi_s[4][256];
    __shared__ __align__(16) float w2_s[256];
    __shared__ __align__(16) float wt_s[4][256];
    __shared__ __align__(16) float ctx_s[4][256];
    __shared__ __align__(16) float sred[4][4][256];   // [wave][n][out]
    __shared__ float part[8][4];

#pragma unroll
    for (int i = 0; i < 4; i++) hi_s[i][t] = hi_ws[(size_t)(bn0 + i) * 256 + t];
    w2_s[t] = W2[t];
    __syncthreads();

    // ---- phase 1: partial scores. wave w: d in [64w,64w+64); lane: m=4*lane..+3
    {
        const float* hjp = hjT + (size_t)b * 65536 + (size_t)(w * 64) * 256 + 4 * lane;
        float sp[4][4];
#pragma unroll
        for (int n = 0; n < 4; n++)
#pragma unroll
            for (int j = 0; j < 4; j++) sp[n][j] = 0.f;

        float4 ha[4], hb[4];
        P1L(ha, 0);
        for (int g = 0; g + 2 < 16; g += 2) {
            P1L(hb, g + 1);
            P1C(ha, g);
            P1L(ha, g + 2);
            P1C(hb, g + 1);
        }
        P1L(hb, 15);
        P1C(ha, 14);
        P1C(hb, 15);

#pragma unroll
        for (int n = 0; n < 4; n++)
            *(float4*)&sred[w][n][4 * lane] =
                make_float4(sp[n][0], sp[n][1], sp[n][2], sp[n][3]);
    }
    __syncthreads();

    // ---- combine + softmax; thread t = m ----
    float b2v = b2[0];
    float s[4];
#pragma unroll
    for (int i = 0; i < 4; i++) {
        s[i] = ((sred[0][i][t] + sred[1][i][t]) +
                (sred[2][i][t] + sred[3][i][t])) + b2v;
        if (t == n0 + i) s[i] = 0.f;   // reference leaves diagonal exactly 0
    }
#pragma unroll
    for (int i = 0; i < 4; i++) {
        float m = wred_max(s[i]);
        if (lane == 0) part[i][w] = m;
    }
    __syncthreads();
    float ev[4];
#pragma unroll
    for (int i = 0; i < 4; i++) {
        float mx = fmaxf(fmaxf(part[i][0], part[i][1]),
                         fmaxf(part[i][2], part[i][3]));
        ev[i] = __expf(s[i] - mx);
        float sm = wred_sum(ev[i]);
        if (lane == 0) part[4 + i][w] = sm;
    }
    __syncthreads();
#pragma unroll
    for (int i = 0; i < 4; i++) {
        float tot = (part[4 + i][0] + part[4 + i][1]) +
                    (part[4 + i][2] + part[4 + i][3]);
        wt_s[i][t] = ev[i] / tot;
    }
    __syncthreads();

    // ---- phase 2: ctx. wave w: m in [64w,64w+64); lane: d=4*lane..+3 ----
    {
        const float* xpp = x + (size_t)b * 65536 + (size_t)(w * 64) * 256 + 4 * lane;
        float cp[4][4];
#pragma unroll
        for (int n = 0; n < 4; n++)
#pragma unroll
            for (int j = 0; j < 4; j++) cp[n][j] = 0.f;

        float4 xa[8], xb[8];
        DLOAD(xa, xpp, 0);
        for (int g = 0; g + 2 < 8; g += 2) {
            DLOAD(xb, xpp, g + 1);
            DCOMP(cp, wt_s, xa, g);
            DLOAD(xa, xpp, g + 2);
            DCOMP(cp, wt_s, xb, g + 1);
        }
        DLOAD(xb, xpp, 7);
        DCOMP(cp, wt_s, xa, 6);
        DCOMP(cp, wt_s, xb, 7);

#pragma unroll
        for (int n = 0; n < 4; n++)
            *(float4*)&sred[w][n][4 * lane] =
                make_float4(cp[n][0], cp[n][1], cp[n][2], cp[n][3]);
    }
    __syncthreads();
#pragma unroll
    for (int i = 0; i < 4; i++)
        ctx_s[i][t] = (sred[0][i][t] + sred[1][i][t]) +
                      (sred[2][i][t] + sred[3][i][t]);
    __syncthreads();

    // ---- phase 3: proj. wave w: d in [64w,64w+64); lane: e=4*lane..+3 ----
    {
        const float* wpp = Wp + (size_t)(w * 64) * 256 + 4 * lane;
        float pq[4][4];
#pragma unroll
        for (int n = 0; n < 4; n++)
#pragma unroll
            for (int j = 0; j < 4; j++) pq[n][j] = 0.f;

        float4 qa4[8], qb4[8];
        DLOAD(qa4, wpp, 0);
        for (int g = 0; g + 2 < 8; g += 2) {
            DLOAD(qb4, wpp, g + 1);
            DCOMP(pq, ctx_s, qa4, g);
            DLOAD(qa4, wpp, g + 2);
            DCOMP(pq, ctx_s, qb4, g + 1);
        }
        DLOAD(qb4, wpp, 7);
        DCOMP(pq, ctx_s, qa4, 6);
        DCOMP(pq, ctx_s, qb4, 7);

#pragma unroll
        for (int n = 0; n < 4; n++)
            *(float4*)&sred[w][n][4 * lane] =
                make_float4(pq[n][0], pq[n][1], pq[n][2], pq[n][3]);
    }
    __syncthreads();

    // ---- combine + LayerNorm + residual; thread t = e ----
    float bpv = bp[t];
    float p[4];
#pragma unroll
    for (int i = 0; i < 4; i++)
        p[i] = ((sred[0][i][t] + sred[1][i][t]) +
                (sred[2][i][t] + sred[3][i][t])) + bpv;

#pragma unroll
    for (int i = 0; i < 4; i++) {
        float su = wred_sum(p[i]);
        float sq = wred_sum(p[i] * p[i]);
        if (lane == 0) { part[i][w] = su; part[4 + i][w] = sq; }
    }
    __syncthreads();
    float gv = gma[t], bv = bta[t];
#pragma unroll
    for (int i = 0; i < 4; i++) {
        float su = (part[i][0] + part[i][1]) + (part[i][2] + part[i][3]);
        float sq = (part[4 + i][0] + part[4 + i][1]) +
                   (part[4 + i][2] + part[4 + i][3]);
        float mu = su * (1.f / 256.f);
        float var = sq * (1.f / 256.f) - mu * mu;
        float ln = (p[i] - mu) * rsqrtf(var + LN_EPS) * gv + bv;
        out[(size_t)(bn0 + i) * 256 + t] = x[(size_t)(bn0 + i) * 256 + t] + ln;
    }
}

extern "C" void kernel_launch(void* const* d_in, const int* in_sizes, int n_in,
                              void* d_out, int out_size, void* d_ws, size_t ws_size,
                              hipStream_t stream) {
    const float* x   = (const float*)d_in[0];
    const float* W1  = (const float*)d_in[1];
    const float* b1  = (const float*)d_in[2];
    const float* W2  = (const float*)d_in[3];
    const float* b2  = (const float*)d_in[4];
    const float* Wp  = (const float*)d_in[5];
    const float* bp  = (const float*)d_in[6];
    const float* gma = (const float*)d_in[7];
    const float* bta = (const float*)d_in[8];
    float* out = (float*)d_out;

    float* hi_ws = (float*)d_ws;                  // [2048,256] f32, 2 MB
    float* hjT   = hi_ws + (size_t)2048 * 256;    // [8,256,256] f32, 2 MB

    k_gemm_hij<<<512, 256, 0, stream>>>(x, W1, b1, hi_ws, hjT);
    k_fused<<<512, 256, 0, stream>>>(x, hi_ws, hjT, W2, b2, Wp, bp,
                                     gma, bta, out);
}